// Round 1
// baseline (454.326 us; speedup 1.0000x reference)
//
#include <hip/hip_runtime.h>

#define N_TOK 16384
#define H_DIM 4096
#define H4    1024      // H/4 (float4 count per row)
#define P_DIM 6
#define E_NUM 64
#define K_TOP 8
#define BLOCK 256
#define GRID  512
#define TOK_PER_BLOCK 32   // N_TOK / GRID
#define TOK_PER_WAVE  8    // 4 waves per block
#define TW 4               // tokens processed together per wave

__launch_bounds__(BLOCK, 1)
__global__ void kdtree_router_kernel(const float* __restrict__ x,
                                     const float* __restrict__ pca_mean,
                                     const float* __restrict__ pca_comp,
                                     const float* __restrict__ centroids,
                                     float* __restrict__ out) {
    // LDS: W staged as [p][h4] float4 (96 KB) + centroids transposed [p][e] + reduce scratch
    __shared__ float4 sW4[P_DIM * H4];
    __shared__ float  sC[P_DIM * E_NUM];
    __shared__ float  sRed[4 * P_DIM];

    const int tid  = threadIdx.x;
    const int wave = tid >> 6;
    const int lane = tid & 63;

    const float4* Wg4   = (const float4*)pca_comp;
    const float4* mean4 = (const float4*)pca_mean;
    const float4* x4    = (const float4*)x;

    // stage centroids transposed: sC[p][e] = centroids[e*6+p]
    for (int i = tid; i < E_NUM * P_DIM; i += BLOCK) {
        int e = i / P_DIM, p = i - e * P_DIM;
        sC[p * E_NUM + e] = centroids[i];
    }

    // stage W into LDS; simultaneously compute mean_proj[p] = mean . W[p]
    #pragma unroll
    for (int p = 0; p < P_DIM; ++p) {
        float sp = 0.f;
        for (int i = tid; i < H4; i += BLOCK) {
            float4 w = Wg4[p * H4 + i];
            sW4[p * H4 + i] = w;
            float4 m = mean4[i];
            sp += w.x * m.x + w.y * m.y + w.z * m.z + w.w * m.w;
        }
        #pragma unroll
        for (int off = 32; off > 0; off >>= 1) sp += __shfl_xor(sp, off, 64);
        if (lane == 0) sRed[wave * P_DIM + p] = sp;
    }
    __syncthreads();

    float mp[P_DIM];
    #pragma unroll
    for (int p = 0; p < P_DIM; ++p)
        mp[p] = sRed[p] + sRed[P_DIM + p] + sRed[2 * P_DIM + p] + sRed[3 * P_DIM + p];

    float* out_idx = out;                       // [N,8] indices (as float)
    float* out_tp  = out + N_TOK * K_TOP;       // [N,8] renormalized top-k probs
    float* out_pr  = out + 2 * N_TOK * K_TOP;   // [N,64] full softmax

    const int tok0 = blockIdx.x * TOK_PER_BLOCK + wave * TOK_PER_WAVE;

    for (int g = 0; g < TOK_PER_WAVE / TW; ++g) {
        const int n0 = tok0 + g * TW;

        float acc[TW][P_DIM];
        #pragma unroll
        for (int t = 0; t < TW; ++t)
            #pragma unroll
            for (int p = 0; p < P_DIM; ++p) acc[t][p] = 0.f;

        // software-pipelined x loads: 4 independent float4 streams per wave
        float4 xc[TW];
        #pragma unroll
        for (int t = 0; t < TW; ++t) xc[t] = x4[(n0 + t) * H4 + lane];

        for (int it = 0; it < H4 / 64; ++it) {
            float4 xn[TW];
            if (it < H4 / 64 - 1) {
                int h4n = (it + 1) * 64 + lane;
                #pragma unroll
                for (int t = 0; t < TW; ++t) xn[t] = x4[(n0 + t) * H4 + h4n];
            }
            const int h4 = it * 64 + lane;
            float4 w[P_DIM];
            #pragma unroll
            for (int p = 0; p < P_DIM; ++p) w[p] = sW4[p * H4 + h4];

            #pragma unroll
            for (int t = 0; t < TW; ++t) {
                #pragma unroll
                for (int p = 0; p < P_DIM; ++p) {
                    acc[t][p] += xc[t].x * w[p].x + xc[t].y * w[p].y
                               + xc[t].z * w[p].z + xc[t].w * w[p].w;
                }
            }
            if (it < H4 / 64 - 1) {
                #pragma unroll
                for (int t = 0; t < TW; ++t) xc[t] = xn[t];
            }
        }

        // per-token epilogue: reduce proj, distances, softmax, top-8
        #pragma unroll
        for (int t = 0; t < TW; ++t) {
            const int n = n0 + t;
            float pr[P_DIM];
            #pragma unroll
            for (int p = 0; p < P_DIM; ++p) {
                float v = acc[t][p];
                #pragma unroll
                for (int off = 32; off > 0; off >>= 1) v += __shfl_xor(v, off, 64);
                pr[p] = v - mp[p];
            }

            // lane e computes distance to centroid e (direct form, >= 0)
            float d2 = 0.f;
            #pragma unroll
            for (int p = 0; p < P_DIM; ++p) {
                float diff = pr[p] - sC[p * E_NUM + lane];
                d2 += diff * diff;
            }
            float dist = sqrtf(d2);

            // softmax(-dist) across 64 lanes
            float mn = dist;
            #pragma unroll
            for (int off = 32; off > 0; off >>= 1) mn = fminf(mn, __shfl_xor(mn, off, 64));
            float ev  = __expf(mn - dist);
            float sum = ev;
            #pragma unroll
            for (int off = 32; off > 0; off >>= 1) sum += __shfl_xor(sum, off, 64);
            float prob = ev / sum;
            out_pr[n * E_NUM + lane] = prob;

            // top-8 via repeated butterfly argmax (ties -> lower index, matches lax.top_k)
            float v = prob; int idx = lane;
            float tsum = 0.f, myv = 0.f; int myi = 0;
            #pragma unroll
            for (int r = 0; r < K_TOP; ++r) {
                float bv = v; int bi = idx;
                #pragma unroll
                for (int off = 32; off > 0; off >>= 1) {
                    float ov = __shfl_xor(bv, off, 64);
                    int   oi = __shfl_xor(bi, off, 64);
                    if (ov > bv || (ov == bv && oi < bi)) { bv = ov; bi = oi; }
                }
                tsum += bv;
                if (lane == r) { myv = bv; myi = bi; }
                if (idx == bi) v = -1.f;   // remove winner (probs are > 0)
            }
            if (lane < K_TOP) {
                out_idx[n * K_TOP + lane] = (float)myi;
                out_tp [n * K_TOP + lane] = myv / tsum;
            }
        }
    }
}

extern "C" void kernel_launch(void* const* d_in, const int* in_sizes, int n_in,
                              void* d_out, int out_size, void* d_ws, size_t ws_size,
                              hipStream_t stream) {
    const float* x         = (const float*)d_in[0];
    const float* pca_mean  = (const float*)d_in[1];
    const float* pca_comp  = (const float*)d_in[2];
    const float* centroids = (const float*)d_in[3];
    // d_in[4] = top_k (known constant 8)
    float* out = (float*)d_out;

    kdtree_router_kernel<<<GRID, BLOCK, 0, stream>>>(x, pca_mean, pca_comp, centroids, out);
}

// Round 2
// 415.041 us; speedup vs baseline: 1.0947x; 1.0947x over previous
//
#include <hip/hip_runtime.h>

#define N_TOK 16384
#define H_DIM 4096
#define H4    1024      // H/4 (float4 count per row)
#define P_DIM 6
#define E_NUM 64
#define K_TOP 8
#define BLOCK 1024      // 16 waves
#define WAVES 16
#define GRID  256       // 1 block per CU
#define TOK_PER_BLOCK 64   // N_TOK / GRID
#define TW 4               // tokens per wave

__launch_bounds__(BLOCK, 4)
__global__ void kdtree_router_kernel(const float* __restrict__ x,
                                     const float* __restrict__ pca_mean,
                                     const float* __restrict__ pca_comp,
                                     const float* __restrict__ centroids,
                                     float* __restrict__ out) {
    // LDS: W staged as [p][h4] float4 (96 KB) + centroids transposed + reduce scratch
    __shared__ float4 sW4[P_DIM * H4];
    __shared__ float  sC[P_DIM * E_NUM];
    __shared__ float  sRed[WAVES * P_DIM];

    const int tid  = threadIdx.x;
    const int wave = tid >> 6;
    const int lane = tid & 63;

    const float4* Wg4   = (const float4*)pca_comp;
    const float4* mean4 = (const float4*)pca_mean;
    const float4* x4    = (const float4*)x;

    // stage centroids transposed: sC[p][e] = centroids[e*6+p]
    if (tid < E_NUM * P_DIM) {
        int e = tid / P_DIM, p = tid - e * P_DIM;
        sC[p * E_NUM + e] = centroids[tid];
    }

    // stage W into LDS (1024 threads -> exactly one float4 per thread per p);
    // simultaneously compute mean_proj[p] = mean . W[p]
    #pragma unroll
    for (int p = 0; p < P_DIM; ++p) {
        float4 w = Wg4[p * H4 + tid];
        sW4[p * H4 + tid] = w;
        float4 m = mean4[tid];
        float sp = w.x * m.x + w.y * m.y + w.z * m.z + w.w * m.w;
        #pragma unroll
        for (int off = 32; off > 0; off >>= 1) sp += __shfl_xor(sp, off, 64);
        if (lane == 0) sRed[wave * P_DIM + p] = sp;
    }
    __syncthreads();

    float mp[P_DIM];
    #pragma unroll
    for (int p = 0; p < P_DIM; ++p) {
        float s = 0.f;
        #pragma unroll
        for (int w = 0; w < WAVES; ++w) s += sRed[w * P_DIM + p];
        mp[p] = s;
    }

    float* out_idx = out;                       // [N,8] indices (as float)
    float* out_tp  = out + N_TOK * K_TOP;       // [N,8] renormalized top-k probs
    float* out_pr  = out + 2 * N_TOK * K_TOP;   // [N,64] full softmax

    const int n0 = blockIdx.x * TOK_PER_BLOCK + wave * TW;

    float acc[TW][P_DIM];
    #pragma unroll
    for (int t = 0; t < TW; ++t)
        #pragma unroll
        for (int p = 0; p < P_DIM; ++p) acc[t][p] = 0.f;

    // software-pipelined x loads: 4 independent float4 streams per wave
    float4 xc[TW];
    #pragma unroll
    for (int t = 0; t < TW; ++t) xc[t] = x4[(n0 + t) * H4 + lane];

    for (int it = 0; it < H4 / 64; ++it) {
        float4 xn[TW];
        if (it < H4 / 64 - 1) {
            int h4n = (it + 1) * 64 + lane;
            #pragma unroll
            for (int t = 0; t < TW; ++t) xn[t] = x4[(n0 + t) * H4 + h4n];
        }
        const int h4 = it * 64 + lane;
        float4 w[P_DIM];
        #pragma unroll
        for (int p = 0; p < P_DIM; ++p) w[p] = sW4[p * H4 + h4];

        #pragma unroll
        for (int t = 0; t < TW; ++t) {
            #pragma unroll
            for (int p = 0; p < P_DIM; ++p) {
                acc[t][p] += xc[t].x * w[p].x + xc[t].y * w[p].y
                           + xc[t].z * w[p].z + xc[t].w * w[p].w;
            }
        }
        if (it < H4 / 64 - 1) {
            #pragma unroll
            for (int t = 0; t < TW; ++t) xc[t] = xn[t];
        }
    }

    // per-token epilogue: reduce proj, distances, softmax, top-8
    #pragma unroll
    for (int t = 0; t < TW; ++t) {
        const int n = n0 + t;
        float pr[P_DIM];
        #pragma unroll
        for (int p = 0; p < P_DIM; ++p) {
            float v = acc[t][p];
            #pragma unroll
            for (int off = 32; off > 0; off >>= 1) v += __shfl_xor(v, off, 64);
            pr[p] = v - mp[p];
        }

        // lane e computes distance to centroid e (direct form, >= 0)
        float d2 = 0.f;
        #pragma unroll
        for (int p = 0; p < P_DIM; ++p) {
            float diff = pr[p] - sC[p * E_NUM + lane];
            d2 += diff * diff;
        }
        float dist = sqrtf(d2);

        // softmax(-dist) across 64 lanes
        float mn = dist;
        #pragma unroll
        for (int off = 32; off > 0; off >>= 1) mn = fminf(mn, __shfl_xor(mn, off, 64));
        float ev  = __expf(mn - dist);
        float sum = ev;
        #pragma unroll
        for (int off = 32; off > 0; off >>= 1) sum += __shfl_xor(sum, off, 64);
        float prob = ev / sum;
        out_pr[n * E_NUM + lane] = prob;

        // top-8 via repeated butterfly argmax (ties -> lower index, matches lax.top_k)
        float v = prob; int idx = lane;
        float tsum = 0.f, myv = 0.f; int myi = 0;
        #pragma unroll
        for (int r = 0; r < K_TOP; ++r) {
            float bv = v; int bi = idx;
            #pragma unroll
            for (int off = 32; off > 0; off >>= 1) {
                float ov = __shfl_xor(bv, off, 64);
                int   oi = __shfl_xor(bi, off, 64);
                if (ov > bv || (ov == bv && oi < bi)) { bv = ov; bi = oi; }
            }
            tsum += bv;
            if (lane == r) { myv = bv; myi = bi; }
            if (idx == bi) v = -1.f;   // remove winner (probs are > 0)
        }
        if (lane < K_TOP) {
            out_idx[n * K_TOP + lane] = (float)myi;
            out_tp [n * K_TOP + lane] = myv / tsum;
        }
    }
}

extern "C" void kernel_launch(void* const* d_in, const int* in_sizes, int n_in,
                              void* d_out, int out_size, void* d_ws, size_t ws_size,
                              hipStream_t stream) {
    const float* x         = (const float*)d_in[0];
    const float* pca_mean  = (const float*)d_in[1];
    const float* pca_comp  = (const float*)d_in[2];
    const float* centroids = (const float*)d_in[3];
    // d_in[4] = top_k (known constant 8)
    float* out = (float*)d_out;

    kdtree_router_kernel<<<GRID, BLOCK, 0, stream>>>(x, pca_mean, pca_comp, centroids, out);
}